// Round 1
// baseline (22336.079 us; speedup 1.0000x reference)
//
#include <hip/hip_runtime.h>

#define UNITS 65
#define SEQ   8192
#define BATCH 50

// fast device math: v_exp_f32-based exp, v_rcp_f32 reciprocal (~1ulp; threshold is 8e-3)
__device__ __forceinline__ float frcp(float x) { return __builtin_amdgcn_rcpf(x); }
__device__ __forceinline__ float fsigmoid(float x) { return frcp(1.0f + __expf(-x)); }
__device__ __forceinline__ float ftanh(float x) {
    // 1 - 2/(exp(2x)+1); stable at both tails (inf -> 1, 0 -> -1)
    float e2 = __expf(2.0f * x);
    return 1.0f - 2.0f * frcp(e2 + 1.0f);
}

// One workgroup per batch element. 512 threads = 8 waves.
// thread t<512: pair p = t>>1 -> column p (0..255), half = t&1 (0: x@W part, 1: h@U part)
// columns 256..259 (o-gate of units 61..64): split-K across each wave (xcol = 256+(wave&3),
//   xhalf = wave>>2), reduced with shfl_xor, partial per wave -> ep[8], summed by update threads.
// update threads: 65 threads spread over waves 0..3 (j = lane*4 + wave), hold c1..c3,h1..h3.
__global__ __launch_bounds__(512)
void lstm3_kernel(const float* __restrict__ x,
                  const float* __restrict__ W,
                  const float* __restrict__ U,
                  const float* __restrict__ b,
                  float* __restrict__ out)
{
    const int e    = blockIdx.x;
    const int tid  = threadIdx.x;
    const int lane = tid & 63;
    const int wave = tid >> 6;

    // inh: [0..64] = input vector, [68..132] = hidden vector (68 so float4 loads stay 16B aligned)
    __shared__ __attribute__((aligned(16))) float inh[136];
    __shared__ float zb[256];   // z for columns 0..255
    __shared__ float ep[8];     // per-wave partials for columns 256..259

    // ---- static roles ----
    const int col  = tid >> 1;          // 0..255
    const int half = tid & 1;
    const int hb   = half * 68;         // LDS base for this half's source vector

    const float* wp = half ? U : W;
    float wu[65];
    #pragma unroll
    for (int k = 0; k < 65; ++k) wu[k] = wp[k * 260 + col];
    const float breg = b[col];

    // extra-column split-K role
    const int xcol  = 256 + (wave & 3);
    const int xhalf = wave >> 2;
    const int xbase = xhalf * 68;
    const float* xp = xhalf ? U : W;
    const float xw1 = xp[lane * 260 + xcol];
    const float xw2 = xp[64 * 260 + xcol];   // k'=64 term, consumed by lane 0

    // update-thread role: unit j = lane*4 + wave (waves 0..3, lanes 0..16)
    const int  j      = lane * 4 + wave;
    const bool is_upd = (wave < 4) && ((lane < 16) || (lane == 16 && wave == 0)); // j in [0,65)
    float bx = 0.0f;
    if (is_upd && j >= 61) bx = b[195 + j];  // bias for extra columns 256..259

    float hs[3] = {0.0f, 0.0f, 0.0f};
    float cs[3] = {0.0f, 0.0f, 0.0f};
    float xnext = 0.0f;

    const float* xrow = x   + (size_t)e * SEQ * UNITS;
    float*       orow = out + (size_t)e * SEQ * UNITS;

    // init: in = x[0], h1 = 0
    if (is_upd) {
        inh[j]      = xrow[j];
        inh[68 + j] = 0.0f;
    }
    __syncthreads();

    for (int t = 0; t < SEQ; ++t) {
        #pragma unroll
        for (int cell = 0; cell < 3; ++cell) {
            // ---------- z phase ----------
            // extra-column partial first (its shfl chain hides behind the main dot)
            float xacc = inh[xbase + lane] * xw1;
            if (lane == 0) xacc += inh[xbase + 64] * xw2;

            // main 65-term half-dot, 4 independent accumulator chains
            float aX = 0.f, aY = 0.f, aZ = 0.f, aW = 0.f;
            const float4* v4 = reinterpret_cast<const float4*>(&inh[hb]);
            #pragma unroll
            for (int k4 = 0; k4 < 16; ++k4) {
                float4 v = v4[k4];
                aX += v.x * wu[4 * k4 + 0];
                aY += v.y * wu[4 * k4 + 1];
                aZ += v.z * wu[4 * k4 + 2];
                aW += v.w * wu[4 * k4 + 3];
            }
            float z = (aX + aY) + (aZ + aW) + inh[hb + 64] * wu[64];

            // combine the (W, U) halves: lanes 2l / 2l+1 hold the two halves of column col
            z += __shfl_xor(z, 1);
            if (half == 0) zb[col] = z + breg;

            // reduce extra-column partial across the wave
            #pragma unroll
            for (int off = 32; off; off >>= 1) xacc += __shfl_xor(xacc, off);
            if (lane == 0) ep[wave] = xacc;

            __syncthreads();

            // ---------- update phase ----------
            if (is_upd) {
                if (cell == 0) {
                    // prefetch next timestep's x row; lands well before it's needed
                    xnext = (t + 1 < SEQ) ? xrow[(size_t)(t + 1) * UNITS + j] : 0.0f;
                }
                float gi = fsigmoid(zb[j]);
                float gf = fsigmoid(zb[65 + j]);
                float gg = ftanh(zb[130 + j]);
                float zo = (j < 61) ? zb[195 + j]
                                    : (ep[j - 61] + ep[j - 61 + 4] + bx);
                float go = fsigmoid(zo);

                float c = gf * cs[cell] + gi * gg;
                float h = go * ftanh(c);
                cs[cell] = c;
                hs[cell] = h;

                if (cell == 0) {            // next: layer 2 (in = h1_new, h = h2_old)
                    inh[j]      = hs[0];
                    inh[68 + j] = hs[1];
                } else if (cell == 1) {     // next: layer 3 (in = h2_new, h = h3_old)
                    inh[j]      = hs[1];
                    inh[68 + j] = hs[2];
                } else {                    // emit h3, set up next timestep's layer 1
                    orow[(size_t)t * UNITS + j] = hs[2];
                    inh[j]      = xnext;
                    inh[68 + j] = hs[0];
                }
            }
            __syncthreads();
        }
    }
}

// Dense head, in place on d_out: out_row = row @ Wd + bd. One thread per row.
__global__ __launch_bounds__(256)
void dense_kernel(float* __restrict__ io,
                  const float* __restrict__ Wd,
                  const float* __restrict__ bd)
{
    __shared__ __attribute__((aligned(16))) float wS[65 * 68];  // padded stride 68 for float4
    __shared__ float bS[65];
    for (int i = threadIdx.x; i < 65 * 65; i += 256) {
        int r = i / 65, c = i - r * 65;
        wS[r * 68 + c] = Wd[i];
    }
    if (threadIdx.x < 65) bS[threadIdx.x] = bd[threadIdx.x];
    __syncthreads();

    const size_t row  = (size_t)blockIdx.x * 256 + threadIdx.x;  // grid sized exactly
    const size_t base = row * 65;

    float r[65];
    #pragma unroll
    for (int k = 0; k < 65; ++k) r[k] = io[base + k];

    for (int ct = 0; ct < 16; ++ct) {   // 16 tiles of 4 columns
        const int c = ct * 4;
        float a0 = bS[c], a1 = bS[c + 1], a2 = bS[c + 2], a3 = bS[c + 3];
        #pragma unroll
        for (int k = 0; k < 65; ++k) {
            const float4 wv = *reinterpret_cast<const float4*>(&wS[k * 68 + c]);
            a0 += r[k] * wv.x;
            a1 += r[k] * wv.y;
            a2 += r[k] * wv.z;
            a3 += r[k] * wv.w;
        }
        io[base + c]     = a0;
        io[base + c + 1] = a1;
        io[base + c + 2] = a2;
        io[base + c + 3] = a3;
    }
    float a = bS[64];
    #pragma unroll
    for (int k = 0; k < 65; ++k) a += r[k] * wS[k * 68 + 64];
    io[base + 64] = a;
}

extern "C" void kernel_launch(void* const* d_in, const int* in_sizes, int n_in,
                              void* d_out, int out_size, void* d_ws, size_t ws_size,
                              hipStream_t stream)
{
    const float* x  = (const float*)d_in[0];
    const float* W  = (const float*)d_in[1];
    const float* U  = (const float*)d_in[2];
    const float* b  = (const float*)d_in[3];
    const float* Wd = (const float*)d_in[4];
    const float* bd = (const float*)d_in[5];
    float* out = (float*)d_out;

    hipLaunchKernelGGL(lstm3_kernel, dim3(BATCH), dim3(512), 0, stream, x, W, U, b, out);
    // 50*8192 = 409600 rows = 1600 blocks * 256 threads, exact
    hipLaunchKernelGGL(dense_kernel, dim3(1600), dim3(256), 0, stream, out, Wd, bd);
}